// Round 1
// baseline (1710.283 us; speedup 1.0000x reference)
//
#include <hip/hip_runtime.h>
#include <math.h>

constexpr int NB=128;
constexpr int NH0=200, NW0=128, NC0=6;
constexpr int NH1=100, NW1=64,  NC1=8;
constexpr int NH2=20,  NW2=32,  NC2=16;
constexpr int NH3=4,   NW3=16,  NC3=32;
constexpr int LAT=4, NPp=11, HID=16, NT=10;
constexpr float BOUNDf=5.0f;
constexpr float LOG2PI=1.8378770664093453f;

__device__ __forceinline__ float softplusf(float v){ return v>20.f ? v : log1pf(expf(v)); }
__device__ __forceinline__ float lrelu(float v){ return v>0.f ? v : 0.01f*v; }

// ---------------- mask0 ----------------
__global__ void k_mask0(const float* __restrict__ x, unsigned char* __restrict__ m0){
  int idx = blockIdx.x*256 + threadIdx.x;
  if (idx >= NB*NH0*NW0) return;
  int b = idx / (NH0*NW0);
  int hw = idx % (NH0*NW0);
  const float* xp = x + (size_t)b*NC0*NH0*NW0 + hw;
  bool any=false;
  #pragma unroll
  for (int c=0;c<NC0;c++) any |= (xp[(size_t)c*NH0*NW0] != 0.0f);
  m0[idx] = any?1:0;
}

// ---------------- conv1 (3x3,6->8) + lrelu + pool 2x2 ----------------
__global__ void k_conv1pool(const float* __restrict__ x, const unsigned char* __restrict__ m0,
                            const float* __restrict__ w1, const float* __restrict__ b1,
                            float* __restrict__ yout, unsigned char* __restrict__ m1){
  int idx = blockIdx.x*256 + threadIdx.x;
  if (idx >= NB*NH1*NW1*NC1) return;
  int co = idx & 7;
  int t = idx >> 3;
  int wp = t % NW1; t /= NW1;
  int hp = t % NH1;
  int b  = t / NH1;
  bool many=false; float best=-1e30f;
  for (int i=0;i<2;i++) for (int j=0;j<2;j++){
    int h = hp*2+i, w = wp*2+j;
    if (!m0[(b*NH0+h)*NW0+w]) continue;
    many = true;
    float acc = b1[co];
    for (int kh=0;kh<3;kh++){
      int hh = h+kh-1; if (hh<0||hh>=NH0) continue;
      for (int kw=0;kw<3;kw++){
        int ww = w+kw-1; if (ww<0||ww>=NW0) continue;
        const float* wp1 = w1 + ((kh*3+kw)*NC0)*NC1 + co;
        #pragma unroll
        for (int ci=0;ci<NC0;ci++)
          acc = fmaf(x[(((size_t)b*NC0+ci)*NH0+hh)*NW0+ww], wp1[ci*NC1], acc);
      }
    }
    best = fmaxf(best, lrelu(acc));
  }
  yout[idx] = many ? best : 0.f;
  if (co==0) m1[(b*NH1+hp)*NW1+wp] = many?1:0;
}

// ---------------- conv2 (3x3,8->16) + lrelu + pool 5x2 ----------------
__global__ void k_conv2pool(const float* __restrict__ yin, const unsigned char* __restrict__ m1,
                            const float* __restrict__ w2, const float* __restrict__ b2,
                            float* __restrict__ yout, unsigned char* __restrict__ m2){
  int idx = blockIdx.x*256 + threadIdx.x;
  if (idx >= NB*NH2*NW2*NC2) return;
  int co = idx & 15;
  int t = idx >> 4;
  int wp = t % NW2; t /= NW2;
  int hp = t % NH2;
  int b  = t / NH2;
  bool many=false; float best=-1e30f;
  for (int i=0;i<5;i++) for (int j=0;j<2;j++){
    int h = hp*5+i, w = wp*2+j;
    if (!m1[(b*NH1+h)*NW1+w]) continue;
    many=true;
    float acc = b2[co];
    for (int kh=0;kh<3;kh++){
      int hh=h+kh-1; if (hh<0||hh>=NH1) continue;
      for (int kw=0;kw<3;kw++){
        int ww=w+kw-1; if (ww<0||ww>=NW1) continue;
        const float* ip  = yin + (((size_t)b*NH1+hh)*NW1+ww)*NC1;
        const float* wpt = w2 + ((kh*3+kw)*NC1)*NC2 + co;
        #pragma unroll
        for (int ci=0;ci<NC1;ci++) acc = fmaf(ip[ci], wpt[ci*NC2], acc);
      }
    }
    best = fmaxf(best, lrelu(acc));
  }
  yout[idx] = many?best:0.f;
  if (co==0) m2[(b*NH2+hp)*NW2+wp] = many?1:0;
}

// ---------------- conv3 (3x3,16->32) + lrelu + pool 5x2 ----------------
__global__ void k_conv3pool(const float* __restrict__ yin, const unsigned char* __restrict__ m2,
                            const float* __restrict__ w3, const float* __restrict__ b3,
                            float* __restrict__ yout, unsigned char* __restrict__ m3){
  int idx = blockIdx.x*256 + threadIdx.x;
  if (idx >= NB*NH3*NW3*NC3) return;
  int co = idx & 31;
  int t = idx >> 5;
  int wp = t % NW3; t /= NW3;
  int hp = t % NH3;
  int b  = t / NH3;
  bool many=false; float best=-1e30f;
  for (int i=0;i<5;i++) for (int j=0;j<2;j++){
    int h = hp*5+i, w = wp*2+j;
    if (!m2[(b*NH2+h)*NW2+w]) continue;
    many=true;
    float acc = b3[co];
    for (int kh=0;kh<3;kh++){
      int hh=h+kh-1; if (hh<0||hh>=NH2) continue;
      for (int kw=0;kw<3;kw++){
        int ww=w+kw-1; if (ww<0||ww>=NW2) continue;
        const float* ip  = yin + (((size_t)b*NH2+hh)*NW2+ww)*NC2;
        const float* wpt = w3 + ((kh*3+kw)*NC2)*NC3 + co;
        #pragma unroll
        for (int ci=0;ci<NC2;ci++) acc = fmaf(ip[ci], wpt[ci*NC3], acc);
      }
    }
    best = fmaxf(best, lrelu(acc));
  }
  yout[idx] = many?best:0.f;
  if (co==0) m3[(b*NH3+hp)*NW3+wp] = many?1:0;
}

// ---------------- latent head + 10-step NSF flow + kld + dec ----------------
__global__ __launch_bounds__(64) void k_latent(
    const float* __restrict__ y3p, const unsigned char* __restrict__ m3,
    const float* __restrict__ eps,
    const float* __restrict__ wmu, const float* __restrict__ bmu,
    const float* __restrict__ wlv, const float* __restrict__ blv,
    const float* __restrict__ wlin, const float* __restrict__ blin,
    const float* __restrict__ fW1, const float* __restrict__ fb1,
    const float* __restrict__ fW2, const float* __restrict__ fb2,
    const float* __restrict__ fW3, const float* __restrict__ fb3,
    float* __restrict__ out_mu, float* __restrict__ out_lv,
    float* __restrict__ out_kld, float* __restrict__ out_zf,
    float* __restrict__ dec)
{
  __shared__ float sW1[NT*HID*LAT];
  __shared__ float sb1[NT*HID];
  __shared__ float sW2[NT*HID*HID];
  __shared__ float sb2[NT*HID];
  __shared__ float sW3[NT*LAT*NPp*HID];
  __shared__ float sb3[NT*LAT*NPp];
  __shared__ float red[64];
  int tid = threadIdx.x;
  for (int i=tid;i<NT*HID*LAT;i+=64){ int j=i&3; int r=(i>>2)%HID; sW1[i]=fW1[i]*(((r%3+1)>=(j+1))?1.f:0.f); }
  for (int i=tid;i<NT*HID;i+=64){ sb1[i]=fb1[i]; sb2[i]=fb2[i]; }
  for (int i=tid;i<NT*HID*HID;i+=64){ int j=i&15; int r=(i>>4)%HID; sW2[i]=fW2[i]*(((r%3+1)>=(j%3+1))?1.f:0.f); }
  for (int i=tid;i<NT*LAT*NPp*HID;i+=64){ int j=i&15; int r=(i>>4)%(LAT*NPp); sW3[i]=fW3[i]*(((r/NPp+1)>(j%3+1))?1.f:0.f); }
  for (int i=tid;i<NT*LAT*NPp;i+=64) sb3[i]=fb3[i];
  __syncthreads();

  int b = blockIdx.x;
  int gpos = b*64 + tid;
  bool msk = m3[gpos]!=0;
  float kld_pc=0.f;
  if (msk){
    float yv[NC3];
    const float* yp = y3p + (size_t)gpos*NC3;
    #pragma unroll
    for (int c=0;c<NC3;c++) yv[c]=yp[c];
    float muv[LAT], lvv[LAT], stdv[LAT], z0[LAT], z[LAT];
    #pragma unroll
    for (int l=0;l<LAT;l++){
      float a=bmu[l], g=blv[l];
      #pragma unroll
      for (int c=0;c<NC3;c++){ a=fmaf(yv[c],wmu[l*NC3+c],a); g=fmaf(yv[c],wlv[l*NC3+c],g); }
      muv[l]=a; lvv[l]=g;
      stdv[l]=expf(0.5f*g);
      z0[l]=fmaf(eps[(size_t)gpos*LAT+l], stdv[l], a);
      z[l]=z0[l];
    }
    float ld_tot=0.f;
    for (int t=0;t<NT;t++){
      float h1[HID], h2[HID];
      const float* W1t = sW1 + t*HID*LAT;
      const float* b1t = sb1 + t*HID;
      #pragma unroll
      for (int i2=0;i2<HID;i2++){
        float a=b1t[i2];
        #pragma unroll
        for (int j2=0;j2<LAT;j2++) a=fmaf(z[j2],W1t[i2*LAT+j2],a);
        h1[i2]=fmaxf(a,0.f);
      }
      const float* W2t = sW2 + t*HID*HID;
      const float* b2t = sb2 + t*HID;
      #pragma unroll
      for (int i2=0;i2<HID;i2++){
        float a=b2t[i2];
        #pragma unroll
        for (int j2=0;j2<HID;j2++) a=fmaf(h1[j2],W2t[i2*HID+j2],a);
        h2[i2]=fmaxf(a,0.f);
      }
      const float* W3t = sW3 + t*LAT*NPp*HID;
      const float* b3t = sb3 + t*LAT*NPp;
      float zn[LAT];
      #pragma unroll
      for (int l=0;l<LAT;l++){
        float p[NPp];
        #pragma unroll
        for (int r=0;r<NPp;r++){
          int rr=l*NPp+r;
          float a=b3t[rr];
          #pragma unroll
          for (int j2=0;j2<HID;j2++) a=fmaf(h2[j2],W3t[rr*HID+j2],a);
          p[r]=a;
        }
        float mw=fmaxf(fmaxf(p[0],p[1]),fmaxf(p[2],p[3]));
        float e0=expf(p[0]-mw), e1=expf(p[1]-mw), e2=expf(p[2]-mw), e3=expf(p[3]-mw);
        float wsc=10.f/(e0+e1+e2+e3);
        float xk1=fmaf(e0,wsc,-BOUNDf), xk2=fmaf(e1,wsc,xk1), xk3=fmaf(e2,wsc,xk2), xk4=fmaf(e3,wsc,xk3);
        float mh=fmaxf(fmaxf(p[4],p[5]),fmaxf(p[6],p[7]));
        float f0=expf(p[4]-mh), f1=expf(p[5]-mh), f2=expf(p[6]-mh), f3=expf(p[7]-mh);
        float hsc=10.f/(f0+f1+f2+f3);
        float yk1=fmaf(f0,hsc,-BOUNDf), yk2=fmaf(f1,hsc,yk1), yk3=fmaf(f2,hsc,yk2), yk4=fmaf(f3,hsc,yk3);
        float dk1=softplusf(p[8]), dk2=softplusf(p[9]), dk3=softplusf(p[10]);
        float xv=z[l];
        bool inside = (xv>=-BOUNDf)&&(xv<=BOUNDf);
        float xc=fminf(fmaxf(xv,-BOUNDf),BOUNDf);
        float x0=-BOUNDf, x1=xk1, y0=-BOUNDf, y1=yk1, d0=1.f, d1=dk1;
        if (xc>=xk1){x0=xk1;x1=xk2;y0=yk1;y1=yk2;d0=dk1;d1=dk2;}
        if (xc>=xk2){x0=xk2;x1=xk3;y0=yk2;y1=yk3;d0=dk2;d1=dk3;}
        if (xc>=xk3){x0=xk3;x1=xk4;y0=yk3;y1=yk4;d0=dk3;d1=1.f;}
        float dxv=x1-x0, dyv=y1-y0;
        float sl=dyv/dxv, ttv=(xc-x0)/dxv, omt=1.f-ttv;
        float den=sl + (d1+d0-2.f*sl)*ttv*omt;
        float yo=y0 + dyv*(sl*ttv*ttv + d0*ttv*omt)/den;
        float ldv=logf(sl*sl*(d1*ttv*ttv + 2.f*sl*ttv*omt + d0*omt*omt)) - 2.f*logf(den);
        zn[l] = inside ? yo : xv;
        ld_tot += inside ? ldv : 0.f;
      }
      if (t<NT-1){ z[0]=zn[3]; z[1]=zn[2]; z[2]=zn[1]; z[3]=zn[0]; }
      else       { z[0]=zn[0]; z[1]=zn[1]; z[2]=zn[2]; z[3]=zn[3]; }
    }
    float lq=0.f, lp=0.f;
    #pragma unroll
    for (int l=0;l<LAT;l++){
      float dv=(z0[l]-muv[l])/stdv[l];
      lq += -0.5f*dv*dv - logf(stdv[l]) - 0.5f*LOG2PI;
      lp += -0.5f*z[l]*z[l] - 0.5f*LOG2PI;
    }
    kld_pc = lq - ld_tot - lp;
    #pragma unroll
    for (int l=0;l<LAT;l++){
      out_mu[(size_t)gpos*LAT+l]=muv[l];
      out_lv[(size_t)gpos*LAT+l]=lvv[l];
      out_zf[(size_t)gpos*LAT+l]=z[l];
    }
    #pragma unroll
    for (int k2=0;k2<NC3;k2++){
      float a=blin[k2];
      #pragma unroll
      for (int l=0;l<LAT;l++) a=fmaf(z[l],wlin[k2*LAT+l],a);
      dec[(size_t)gpos*NC3+k2]=a;
    }
  } else {
    #pragma unroll
    for (int l=0;l<LAT;l++){
      out_mu[(size_t)gpos*LAT+l]=0.f;
      out_lv[(size_t)gpos*LAT+l]=0.f;
      out_zf[(size_t)gpos*LAT+l]=0.f;
    }
    for (int k2=0;k2<NC3;k2++) dec[(size_t)gpos*NC3+k2]=0.f;
  }
  red[tid]=kld_pc;
  __syncthreads();
  for (int s=32;s>0;s>>=1){ if (tid<s) red[tid]+=red[tid+s]; __syncthreads(); }
  if (tid==0) out_kld[b]=red[0];
}

// ---------------- invconv1 (5,2,32,32): (4,16)->(20,32), mask m2 ----------------
__global__ void k_inv1(const float* __restrict__ dec, const unsigned char* __restrict__ m2,
                       const float* __restrict__ u1, const float* __restrict__ bu1,
                       float* __restrict__ t1){
  int idx = blockIdx.x*256+threadIdx.x;
  if (idx >= NB*NH2*NW2*NC3) return;
  int co = idx & 31;
  int t = idx >> 5;
  int w = t % NW2; t /= NW2;
  int h = t % NH2;
  int b = t / NH2;
  float v=0.f;
  if (m2[(b*NH2+h)*NW2+w]){
    const float* dp = dec + (((size_t)b*NH3 + h/5)*NW3 + w/2)*NC3;
    const float* up = u1 + (((h%5)*2+(w%2))*NC3)*NC3 + co;
    v = bu1[co];
    #pragma unroll
    for (int c=0;c<NC3;c++) v=fmaf(dp[c],up[c*NC3],v);
  }
  t1[idx]=v;
}

// ---------------- conv4 (3x3,32->16), mask m2, no act ----------------
__global__ void k_conv4(const float* __restrict__ yin, const unsigned char* __restrict__ m2,
                        const float* __restrict__ w4, const float* __restrict__ b4,
                        float* __restrict__ t2){
  int idx = blockIdx.x*256+threadIdx.x;
  if (idx >= NB*NH2*NW2*NC2) return;
  int co = idx & 15;
  int t = idx >> 4;
  int w = t % NW2; t /= NW2;
  int h = t % NH2;
  int b = t / NH2;
  float v=0.f;
  if (m2[(b*NH2+h)*NW2+w]){
    v=b4[co];
    for (int kh=0;kh<3;kh++){
      int hh=h+kh-1; if (hh<0||hh>=NH2) continue;
      for (int kw=0;kw<3;kw++){
        int ww=w+kw-1; if (ww<0||ww>=NW2) continue;
        const float* ip  = yin + (((size_t)b*NH2+hh)*NW2+ww)*NC3;
        const float* wpt = w4 + ((kh*3+kw)*NC3)*NC2 + co;
        #pragma unroll
        for (int ci=0;ci<NC3;ci++) v=fmaf(ip[ci],wpt[ci*NC2],v);
      }
    }
  }
  t2[idx]=v;
}

// ---------------- invconv2 (5,2,16,16): (20,32)->(100,64), mask m1 ----------------
__global__ void k_inv2(const float* __restrict__ tin, const unsigned char* __restrict__ m1,
                       const float* __restrict__ u2, const float* __restrict__ bu2,
                       float* __restrict__ t3){
  int idx = blockIdx.x*256+threadIdx.x;
  if (idx >= NB*NH1*NW1*NC2) return;
  int co = idx & 15;
  int t = idx >> 4;
  int w = t % NW1; t /= NW1;
  int h = t % NH1;
  int b = t / NH1;
  float v=0.f;
  if (m1[(b*NH1+h)*NW1+w]){
    const float* dp = tin + (((size_t)b*NH2 + h/5)*NW2 + w/2)*NC2;
    const float* up = u2 + (((h%5)*2+(w%2))*NC2)*NC2 + co;
    v = bu2[co];
    #pragma unroll
    for (int c=0;c<NC2;c++) v=fmaf(dp[c],up[c*NC2],v);
  }
  t3[idx]=v;
}

// ---------------- conv5 (3x3,16->8), mask m1 ----------------
__global__ void k_conv5(const float* __restrict__ yin, const unsigned char* __restrict__ m1,
                        const float* __restrict__ w5, const float* __restrict__ b5,
                        float* __restrict__ t4){
  int idx = blockIdx.x*256+threadIdx.x;
  if (idx >= NB*NH1*NW1*NC1) return;
  int co = idx & 7;
  int t = idx >> 3;
  int w = t % NW1; t /= NW1;
  int h = t % NH1;
  int b = t / NH1;
  float v=0.f;
  if (m1[(b*NH1+h)*NW1+w]){
    v=b5[co];
    for (int kh=0;kh<3;kh++){
      int hh=h+kh-1; if (hh<0||hh>=NH1) continue;
      for (int kw=0;kw<3;kw++){
        int ww=w+kw-1; if (ww<0||ww>=NW1) continue;
        const float* ip  = yin + (((size_t)b*NH1+hh)*NW1+ww)*NC2;
        const float* wpt = w5 + ((kh*3+kw)*NC2)*NC1 + co;
        #pragma unroll
        for (int ci=0;ci<NC2;ci++) v=fmaf(ip[ci],wpt[ci*NC1],v);
      }
    }
  }
  t4[idx]=v;
}

// ---------------- fused invconv3 (2,2,8,8) + conv6 (3x3,8->6), mask m0, NCHW out ----------------
__global__ void k_inv3conv6(const float* __restrict__ t4, const unsigned char* __restrict__ m0,
                            const float* __restrict__ u3, const float* __restrict__ bu3,
                            const float* __restrict__ w6, const float* __restrict__ b6,
                            float* __restrict__ out){
  int idx = blockIdx.x*256+threadIdx.x;
  if (idx >= NB*NH0*NW0) return;
  int w = idx % NW0;
  int t = idx / NW0;
  int h = t % NH0;
  int b = t / NH0;
  float acc[6];
  if (m0[idx]){
    #pragma unroll
    for (int co=0;co<6;co++) acc[co]=b6[co];
    for (int kh=0;kh<3;kh++){
      int hh=h+kh-1; if (hh<0||hh>=NH0) continue;
      for (int kw=0;kw<3;kw++){
        int ww=w+kw-1; if (ww<0||ww>=NW0) continue;
        if (!m0[(b*NH0+hh)*NW0+ww]) continue;
        // invconv3 pixel value (8 channels)
        const float* tp = t4 + (((size_t)b*NH1 + (hh>>1))*NW1 + (ww>>1))*NC1;
        const float* up = u3 + (((hh&1)*2+(ww&1))*NC1)*NC1;
        float v8[NC1];
        #pragma unroll
        for (int c=0;c<NC1;c++){
          float v=bu3[c];
          #pragma unroll
          for (int ci=0;ci<NC1;ci++) v=fmaf(tp[ci],up[ci*NC1+c],v);
          v8[c]=v;
        }
        const float* wpt = w6 + ((kh*3+kw)*NC1)*6;
        #pragma unroll
        for (int ci=0;ci<NC1;ci++)
          #pragma unroll
          for (int co=0;co<6;co++) acc[co]=fmaf(v8[ci],wpt[ci*6+co],acc[co]);
      }
    }
  } else {
    #pragma unroll
    for (int co=0;co<6;co++) acc[co]=0.f;
  }
  size_t base = (size_t)b*6*NH0*NW0 + (size_t)h*NW0 + w;
  #pragma unroll
  for (int co=0;co<6;co++) out[base + (size_t)co*NH0*NW0] = acc[co];
}

extern "C" void kernel_launch(void* const* d_in, const int* in_sizes, int n_in,
                              void* d_out, int out_size, void* d_ws, size_t ws_size,
                              hipStream_t stream){
  (void)in_sizes; (void)n_in; (void)out_size; (void)ws_size;
  const float* x    = (const float*)d_in[0];
  const float* eps  = (const float*)d_in[1];
  const float* w1   = (const float*)d_in[2];
  const float* b1   = (const float*)d_in[3];
  const float* w2   = (const float*)d_in[4];
  const float* b2   = (const float*)d_in[5];
  const float* w3   = (const float*)d_in[6];
  const float* b3   = (const float*)d_in[7];
  const float* wmu  = (const float*)d_in[8];
  const float* bmu  = (const float*)d_in[9];
  const float* wlv  = (const float*)d_in[10];
  const float* blv  = (const float*)d_in[11];
  const float* wlin = (const float*)d_in[12];
  const float* blin = (const float*)d_in[13];
  const float* u1   = (const float*)d_in[14];
  const float* bu1  = (const float*)d_in[15];
  const float* w4   = (const float*)d_in[16];
  const float* b4   = (const float*)d_in[17];
  const float* u2   = (const float*)d_in[18];
  const float* bu2  = (const float*)d_in[19];
  const float* w5   = (const float*)d_in[20];
  const float* b5   = (const float*)d_in[21];
  const float* u3   = (const float*)d_in[22];
  const float* bu3  = (const float*)d_in[23];
  const float* w6   = (const float*)d_in[24];
  const float* b6   = (const float*)d_in[25];
  const float* fW1  = (const float*)d_in[26];
  const float* fb1  = (const float*)d_in[27];
  const float* fW2  = (const float*)d_in[28];
  const float* fb2  = (const float*)d_in[29];
  const float* fW3  = (const float*)d_in[30];
  const float* fb3  = (const float*)d_in[31];

  char* ws = (char*)d_ws;
  unsigned char* m0 = (unsigned char*)(ws);
  unsigned char* m1 = (unsigned char*)(ws + 3276800);
  unsigned char* m2 = (unsigned char*)(ws + 4096000);
  unsigned char* m3 = (unsigned char*)(ws + 4177920);
  float* y1p = (float*)(ws + 4194304);    // 26,214,400 B
  float* y2p = (float*)(ws + 30408704);   //  5,242,880 B
  float* y3p = (float*)(ws + 35651584);   //  1,048,576 B
  float* dec = (float*)(ws + 36700160);   //  1,048,576 B
  float* t1  = (float*)(ws + 37748736);   // 10,485,760 B
  float* t3  = (float*)(ws + 48234496);   // 52,428,800 B  (end = 100,663,296)
  float* t2  = y2p;  // reuse: y2p dead after k_conv3pool
  float* t4  = y1p;  // reuse: y1p dead after k_conv2pool

  float* out   = (float*)d_out;
  float* o_mu  = out + 19660800;
  float* o_lv  = out + 19693568;
  float* o_kld = out + 19726336;
  float* o_zf  = out + 19726464;

  k_mask0    <<<12800,256,0,stream>>>(x, m0);
  k_conv1pool<<<25600,256,0,stream>>>(x, m0, w1, b1, y1p, m1);
  k_conv2pool<<< 5120,256,0,stream>>>(y1p, m1, w2, b2, y2p, m2);
  k_conv3pool<<< 1024,256,0,stream>>>(y2p, m2, w3, b3, y3p, m3);
  k_latent   <<<  128, 64,0,stream>>>(y3p, m3, eps, wmu,bmu,wlv,blv,wlin,blin,
                                      fW1,fb1,fW2,fb2,fW3,fb3, o_mu,o_lv,o_kld,o_zf, dec);
  k_inv1     <<<10240,256,0,stream>>>(dec, m2, u1, bu1, t1);
  k_conv4    <<< 5120,256,0,stream>>>(t1, m2, w4, b4, t2);
  k_inv2     <<<51200,256,0,stream>>>(t2, m1, u2, bu2, t3);
  k_conv5    <<<25600,256,0,stream>>>(t3, m1, w5, b5, t4);
  k_inv3conv6<<<12800,256,0,stream>>>(t4, m0, u3, bu3, w6, b6, out);
}

// Round 2
// 1355.739 us; speedup vs baseline: 1.2615x; 1.2615x over previous
//
#include <hip/hip_runtime.h>
#include <math.h>

constexpr int NB=128;
constexpr int NH0=200, NW0=128, NC0=6;
constexpr int NH1=100, NW1=64,  NC1=8;
constexpr int NH2=20,  NW2=32,  NC2=16;
constexpr int NH3=4,   NW3=16,  NC3=32;
constexpr int LAT=4, NPp=11, HID=16, NT=10;
constexpr float BOUNDf=5.0f;
constexpr float LOG2PI=1.8378770664093453f;

__device__ __forceinline__ float fexpf(float v){ return __expf(v); }
__device__ __forceinline__ float flogf(float v){ return __logf(v); }
__device__ __forceinline__ float softplusf(float v){ return v>20.f ? v : __logf(1.f+__expf(v)); }
__device__ __forceinline__ float lrelu(float v){ return v>0.f ? v : 0.01f*v; }

// ============ conv1 (3x3,6->8) + lrelu + pool2x2, LDS-tiled, computes m0,m1 ============
// tile: 16x16 pool outputs  -> input 34x34 (incl. halo)
__global__ __launch_bounds__(256) void k_conv1pool(
    const float* __restrict__ x, const float* __restrict__ w1, const float* __restrict__ b1,
    float* __restrict__ y1p, unsigned char* __restrict__ m0, unsigned char* __restrict__ m1){
  __shared__ float xs[6][34][34];
  __shared__ float ws1[54][8];
  __shared__ unsigned char ms[34][34];
  int blk = blockIdx.x;
  int b  = blk / 28;
  int t  = blk % 28;
  int th = t / 4, tw = t % 4;
  int hp0 = th*16, wp0 = tw*16;
  int h0 = hp0*2 - 1, w0 = wp0*2 - 1;
  int tid = threadIdx.x;
  for (int i=tid;i<432;i+=256) ws1[i>>3][i&7] = w1[i];
  for (int i=tid;i<6*34*34;i+=256){
    int ci=i/1156; int rem=i-ci*1156; int r=rem/34, c=rem-r*34;
    int h=h0+r, w=w0+c;
    float v=0.f;
    if (h>=0 && h<NH0 && w>=0 && w<NW0) v = x[((size_t)(b*NC0+ci)*NH0+h)*NW0+w];
    xs[ci][r][c]=v;
  }
  __syncthreads();
  for (int i=tid;i<1156;i+=256){
    int r=i/34, c=i-r*34;
    bool any=false;
    #pragma unroll
    for (int ci=0;ci<6;ci++) any |= (xs[ci][r][c]!=0.f);
    ms[r][c] = any?1:0;
  }
  __syncthreads();
  // write m0 for the 32x32 interior (disjoint across tiles)
  for (int i=tid;i<1024;i+=256){
    int r=(i>>5)+1, c=(i&31)+1;
    int h=h0+r, w=w0+c;
    if (h<NH0) m0[(b*NH0+h)*NW0+w] = ms[r][c];
  }
  // compute: one (hp,wp) per thread, all 8 co
  int lhp = tid>>4, lwp = tid&15;
  int hp = hp0+lhp, wp = wp0+lwp;
  if (hp < NH1){
    float best[8];
    #pragma unroll
    for (int co=0;co<8;co++) best[co]=-1e30f;
    float bb[8];
    #pragma unroll
    for (int co=0;co<8;co++) bb[co]=b1[co];
    bool many=false;
    #pragma unroll
    for (int i=0;i<2;i++)
    #pragma unroll
    for (int j=0;j<2;j++){
      int r = lhp*2+i+1, c = lwp*2+j+1;
      if (!ms[r][c]) continue;
      many=true;
      float a[8];
      #pragma unroll
      for (int co=0;co<8;co++) a[co]=bb[co];
      #pragma unroll
      for (int kh=0;kh<3;kh++)
      #pragma unroll
      for (int kw=0;kw<3;kw++)
      #pragma unroll
      for (int ci=0;ci<6;ci++){
        float v = xs[ci][r-1+kh][c-1+kw];
        const float* wv = ws1[(kh*3+kw)*6+ci];
        #pragma unroll
        for (int co=0;co<8;co++) a[co]=fmaf(v,wv[co],a[co]);
      }
      #pragma unroll
      for (int co=0;co<8;co++) best[co]=fmaxf(best[co], lrelu(a[co]));
    }
    float* yp = y1p + (((size_t)b*NH1+hp)*NW1+wp)*8;
    #pragma unroll
    for (int co=0;co<8;co++) yp[co] = many?best[co]:0.f;
    m1[(b*NH1+hp)*NW1+wp] = many?1:0;
  }
}

// ============ conv2 (3x3,8->16) + lrelu + pool 5x2 ============
__global__ void k_conv2pool(const float* __restrict__ yin, const unsigned char* __restrict__ m1,
                            const float* __restrict__ w2, const float* __restrict__ b2,
                            float* __restrict__ yout, unsigned char* __restrict__ m2){
  int idx = blockIdx.x*256 + threadIdx.x;
  if (idx >= NB*NH2*NW2*NC2) return;
  int co = idx & 15;
  int t = idx >> 4;
  int wp = t % NW2; t /= NW2;
  int hp = t % NH2;
  int b  = t / NH2;
  bool many=false; float best=-1e30f;
  for (int i=0;i<5;i++) for (int j=0;j<2;j++){
    int h = hp*5+i, w = wp*2+j;
    if (!m1[(b*NH1+h)*NW1+w]) continue;
    many=true;
    float acc = b2[co];
    for (int kh=0;kh<3;kh++){
      int hh=h+kh-1; if (hh<0||hh>=NH1) continue;
      for (int kw=0;kw<3;kw++){
        int ww=w+kw-1; if (ww<0||ww>=NW1) continue;
        const float* ip  = yin + (((size_t)b*NH1+hh)*NW1+ww)*NC1;
        const float* wpt = w2 + ((kh*3+kw)*NC1)*NC2 + co;
        #pragma unroll
        for (int ci=0;ci<NC1;ci++) acc = fmaf(ip[ci], wpt[ci*NC2], acc);
      }
    }
    best = fmaxf(best, lrelu(acc));
  }
  yout[idx] = many?best:0.f;
  if (co==0) m2[(b*NH2+hp)*NW2+wp] = many?1:0;
}

// ============ conv3 (3x3,16->32) + lrelu + pool 5x2 ============
__global__ void k_conv3pool(const float* __restrict__ yin, const unsigned char* __restrict__ m2,
                            const float* __restrict__ w3, const float* __restrict__ b3,
                            float* __restrict__ yout, unsigned char* __restrict__ m3){
  int idx = blockIdx.x*256 + threadIdx.x;
  if (idx >= NB*NH3*NW3*NC3) return;
  int co = idx & 31;
  int t = idx >> 5;
  int wp = t % NW3; t /= NW3;
  int hp = t % NH3;
  int b  = t / NH3;
  bool many=false; float best=-1e30f;
  for (int i=0;i<5;i++) for (int j=0;j<2;j++){
    int h = hp*5+i, w = wp*2+j;
    if (!m2[(b*NH2+h)*NW2+w]) continue;
    many=true;
    float acc = b3[co];
    for (int kh=0;kh<3;kh++){
      int hh=h+kh-1; if (hh<0||hh>=NH2) continue;
      for (int kw=0;kw<3;kw++){
        int ww=w+kw-1; if (ww<0||ww>=NW2) continue;
        const float* ip  = yin + (((size_t)b*NH2+hh)*NW2+ww)*NC2;
        const float* wpt = w3 + ((kh*3+kw)*NC2)*NC3 + co;
        #pragma unroll
        for (int ci=0;ci<NC2;ci++) acc = fmaf(ip[ci], wpt[ci*NC3], acc);
      }
    }
    best = fmaxf(best, lrelu(acc));
  }
  yout[idx] = many?best:0.f;
  if (co==0) m3[(b*NH3+hp)*NW3+wp] = many?1:0;
}

// ============ latent head + NSF flow + kld + dec ============
__global__ __launch_bounds__(64) void k_latent(
    const float* __restrict__ y3p, const unsigned char* __restrict__ m3,
    const float* __restrict__ eps,
    const float* __restrict__ wmu, const float* __restrict__ bmu,
    const float* __restrict__ wlv, const float* __restrict__ blv,
    const float* __restrict__ wlin, const float* __restrict__ blin,
    const float* __restrict__ fW1, const float* __restrict__ fb1,
    const float* __restrict__ fW2, const float* __restrict__ fb2,
    const float* __restrict__ fW3, const float* __restrict__ fb3,
    float* __restrict__ out_mu, float* __restrict__ out_lv,
    float* __restrict__ out_kld, float* __restrict__ out_zf,
    float* __restrict__ dec)
{
  __shared__ __align__(16) float sW1[NT*HID*LAT];
  __shared__ float sb1[NT*HID];
  __shared__ __align__(16) float sW2[NT*HID*HID];
  __shared__ float sb2[NT*HID];
  __shared__ __align__(16) float sW3[NT*LAT*NPp*HID];
  __shared__ float sb3[NT*LAT*NPp];
  __shared__ float red[64];
  int tid = threadIdx.x;
  for (int i=tid;i<NT*HID*LAT;i+=64){ int j=i&3; int r=(i>>2)%HID; sW1[i]=fW1[i]*(((r%3+1)>=(j+1))?1.f:0.f); }
  for (int i=tid;i<NT*HID;i+=64){ sb1[i]=fb1[i]; sb2[i]=fb2[i]; }
  for (int i=tid;i<NT*HID*HID;i+=64){ int j=i&15; int r=(i>>4)%HID; sW2[i]=fW2[i]*(((r%3+1)>=(j%3+1))?1.f:0.f); }
  for (int i=tid;i<NT*LAT*NPp*HID;i+=64){ int j=i&15; int r=(i>>4)%(LAT*NPp); sW3[i]=fW3[i]*(((r/NPp+1)>(j%3+1))?1.f:0.f); }
  for (int i=tid;i<NT*LAT*NPp;i+=64) sb3[i]=fb3[i];
  __syncthreads();

  int b = blockIdx.x;
  int gpos = b*64 + tid;
  bool msk = m3[gpos]!=0;
  float kld_pc=0.f;
  if (msk){
    float yv[NC3];
    const float* yp = y3p + (size_t)gpos*NC3;
    #pragma unroll
    for (int c=0;c<NC3;c++) yv[c]=yp[c];
    float muv[LAT], lvv[LAT], stdv[LAT], evv[LAT], z0[LAT], z[LAT];
    #pragma unroll
    for (int l=0;l<LAT;l++){
      float a=bmu[l], g=blv[l];
      #pragma unroll
      for (int c=0;c<NC3;c++){ a=fmaf(yv[c],wmu[l*NC3+c],a); g=fmaf(yv[c],wlv[l*NC3+c],g); }
      muv[l]=a; lvv[l]=g;
      stdv[l]=fexpf(0.5f*g);
      evv[l]=eps[(size_t)gpos*LAT+l];
      z0[l]=fmaf(evv[l], stdv[l], a);
      z[l]=z0[l];
    }
    float ld_tot=0.f;
    for (int t=0;t<NT;t++){
      float h1[HID], h2[HID];
      const float* W1t = sW1 + t*HID*LAT;
      const float* b1t = sb1 + t*HID;
      float4 zv = make_float4(z[0],z[1],z[2],z[3]);
      #pragma unroll
      for (int i2=0;i2<HID;i2++){
        float4 wr = *(const float4*)(W1t + i2*4);
        float a = b1t[i2];
        a = fmaf(zv.x,wr.x, fmaf(zv.y,wr.y, fmaf(zv.z,wr.z, fmaf(zv.w,wr.w, a))));
        h1[i2]=fmaxf(a,0.f);
      }
      const float* W2t = sW2 + t*HID*HID;
      const float* b2t = sb2 + t*HID;
      #pragma unroll
      for (int i2=0;i2<HID;i2++){
        float a=b2t[i2];
        const float4* wr = (const float4*)(W2t + i2*HID);
        #pragma unroll
        for (int q=0;q<4;q++){
          float4 w4 = wr[q];
          a = fmaf(h1[q*4+0],w4.x, fmaf(h1[q*4+1],w4.y, fmaf(h1[q*4+2],w4.z, fmaf(h1[q*4+3],w4.w, a))));
        }
        h2[i2]=fmaxf(a,0.f);
      }
      const float* W3t = sW3 + t*LAT*NPp*HID;
      const float* b3t = sb3 + t*LAT*NPp;
      float zn[LAT];
      #pragma unroll
      for (int l=0;l<LAT;l++){
        float p[NPp];
        #pragma unroll
        for (int r=0;r<NPp;r++){
          int rr=l*NPp+r;
          float a=b3t[rr];
          const float4* wr = (const float4*)(W3t + rr*HID);
          #pragma unroll
          for (int q=0;q<4;q++){
            float4 w4 = wr[q];
            a = fmaf(h2[q*4+0],w4.x, fmaf(h2[q*4+1],w4.y, fmaf(h2[q*4+2],w4.z, fmaf(h2[q*4+3],w4.w, a))));
          }
          p[r]=a;
        }
        float mw=fmaxf(fmaxf(p[0],p[1]),fmaxf(p[2],p[3]));
        float e0=fexpf(p[0]-mw), e1=fexpf(p[1]-mw), e2=fexpf(p[2]-mw), e3=fexpf(p[3]-mw);
        float wsc=10.f/(e0+e1+e2+e3);
        float xk1=fmaf(e0,wsc,-BOUNDf), xk2=fmaf(e1,wsc,xk1), xk3=fmaf(e2,wsc,xk2), xk4=fmaf(e3,wsc,xk3);
        float mh=fmaxf(fmaxf(p[4],p[5]),fmaxf(p[6],p[7]));
        float f0=fexpf(p[4]-mh), f1=fexpf(p[5]-mh), f2=fexpf(p[6]-mh), f3=fexpf(p[7]-mh);
        float hsc=10.f/(f0+f1+f2+f3);
        float yk1=fmaf(f0,hsc,-BOUNDf), yk2=fmaf(f1,hsc,yk1), yk3=fmaf(f2,hsc,yk2), yk4=fmaf(f3,hsc,yk3);
        float dk1=softplusf(p[8]), dk2=softplusf(p[9]), dk3=softplusf(p[10]);
        float xv=z[l];
        bool inside = (xv>=-BOUNDf)&&(xv<=BOUNDf);
        float xc=fminf(fmaxf(xv,-BOUNDf),BOUNDf);
        float x0=-BOUNDf, x1=xk1, y0=-BOUNDf, y1=yk1, d0=1.f, d1=dk1;
        if (xc>=xk1){x0=xk1;x1=xk2;y0=yk1;y1=yk2;d0=dk1;d1=dk2;}
        if (xc>=xk2){x0=xk2;x1=xk3;y0=yk2;y1=yk3;d0=dk2;d1=dk3;}
        if (xc>=xk3){x0=xk3;x1=xk4;y0=yk3;y1=yk4;d0=dk3;d1=1.f;}
        float dxv=x1-x0, dyv=y1-y0;
        float sl=dyv/dxv, ttv=(xc-x0)/dxv, omt=1.f-ttv;
        float den=sl + (d1+d0-2.f*sl)*ttv*omt;
        float yo=y0 + dyv*(sl*ttv*ttv + d0*ttv*omt)/den;
        float ldv=flogf(sl*sl*(d1*ttv*ttv + 2.f*sl*ttv*omt + d0*omt*omt)) - 2.f*flogf(den);
        zn[l] = inside ? yo : xv;
        ld_tot += inside ? ldv : 0.f;
      }
      if (t<NT-1){ z[0]=zn[3]; z[1]=zn[2]; z[2]=zn[1]; z[3]=zn[0]; }
      else       { z[0]=zn[0]; z[1]=zn[1]; z[2]=zn[2]; z[3]=zn[3]; }
    }
    float lq=0.f, lp=0.f;
    #pragma unroll
    for (int l=0;l<LAT;l++){
      lq += -0.5f*evv[l]*evv[l] - 0.5f*lvv[l] - 0.5f*LOG2PI;
      lp += -0.5f*z[l]*z[l] - 0.5f*LOG2PI;
    }
    kld_pc = lq - ld_tot - lp;
    #pragma unroll
    for (int l=0;l<LAT;l++){
      out_mu[(size_t)gpos*LAT+l]=muv[l];
      out_lv[(size_t)gpos*LAT+l]=lvv[l];
      out_zf[(size_t)gpos*LAT+l]=z[l];
    }
    #pragma unroll
    for (int k2=0;k2<NC3;k2++){
      float a=blin[k2];
      #pragma unroll
      for (int l=0;l<LAT;l++) a=fmaf(z[l],wlin[k2*LAT+l],a);
      dec[(size_t)gpos*NC3+k2]=a;
    }
  } else {
    #pragma unroll
    for (int l=0;l<LAT;l++){
      out_mu[(size_t)gpos*LAT+l]=0.f;
      out_lv[(size_t)gpos*LAT+l]=0.f;
      out_zf[(size_t)gpos*LAT+l]=0.f;
    }
    for (int k2=0;k2<NC3;k2++) dec[(size_t)gpos*NC3+k2]=0.f;
  }
  red[tid]=kld_pc;
  __syncthreads();
  for (int s=32;s>0;s>>=1){ if (tid<s) red[tid]+=red[tid+s]; __syncthreads(); }
  if (tid==0) out_kld[b]=red[0];
}

// ============ fused invconv1(5,2,32,32) + conv4(3x3,32->16) -> t2, mask m2 ============
// tile 10x16 of (20x32); halo 12x18 staged in LDS
__global__ __launch_bounds__(256) void k_ic4(
    const float* __restrict__ dec, const unsigned char* __restrict__ m2,
    const float* __restrict__ u1, const float* __restrict__ bu1,
    const float* __restrict__ w4, const float* __restrict__ b4,
    float* __restrict__ t2){
  __shared__ __align__(16) float vs[12][18][32];
  __shared__ __align__(16) float w4s[288][16];
  __shared__ unsigned char msl[12][18];
  int blk = blockIdx.x;
  int b  = blk >> 2;
  int t  = blk & 3;
  int th = t >> 1, tw = t & 1;
  int h0 = th*10, w0 = tw*16;
  int tid = threadIdx.x;
  for (int i=tid;i<288*16;i+=256) w4s[i>>4][i&15] = w4[i];
  if (tid < 216){
    int lr = tid/18, lc = tid%18;
    int h2 = h0-1+lr, w2 = w0-1+lc;
    bool mk = (h2>=0 && h2<NH2 && w2>=0 && w2<NW2) && m2[(b*NH2+h2)*NW2+w2];
    msl[lr][lc] = mk?1:0;
    float acc[32];
    if (mk){
      const float* dp = dec + (((size_t)b*NH3 + h2/5)*NW3 + w2/2)*NC3;
      const float* up = u1 + ((h2%5)*2 + (w2&1))*1024;
      #pragma unroll
      for (int co=0;co<32;co++) acc[co]=bu1[co];
      #pragma unroll
      for (int ci=0;ci<32;ci++){
        float dv = dp[ci];
        const float* ur = up + ci*32;
        #pragma unroll
        for (int co=0;co<32;co++) acc[co]=fmaf(dv,ur[co],acc[co]);
      }
    } else {
      #pragma unroll
      for (int co=0;co<32;co++) acc[co]=0.f;
    }
    #pragma unroll
    for (int co=0;co<32;co++) vs[lr][lc][co]=acc[co];
  }
  __syncthreads();
  if (tid < 160){
    int lh = tid/16, lw = tid%16;
    int h2 = h0+lh, w2 = w0+lw;
    float a[16];
    if (msl[lh+1][lw+1]){
      #pragma unroll
      for (int co=0;co<16;co++) a[co]=b4[co];
      #pragma unroll
      for (int kh=0;kh<3;kh++)
      #pragma unroll
      for (int kw=0;kw<3;kw++){
        const float* vp = vs[lh+kh][lw+kw];
        #pragma unroll
        for (int ci=0;ci<32;ci++){
          float v = vp[ci];
          const float* wr = w4s[(kh*3+kw)*32+ci];
          #pragma unroll
          for (int co=0;co<16;co++) a[co]=fmaf(v,wr[co],a[co]);
        }
      }
    } else {
      #pragma unroll
      for (int co=0;co<16;co++) a[co]=0.f;
    }
    float* op = t2 + (((size_t)b*NH2+h2)*NW2+w2)*NC2;
    #pragma unroll
    for (int co=0;co<16;co++) op[co]=a[co];
  }
}

// ============ fused invconv2(5,2,16,16) + conv5(3x3,16->8) -> t4, mask m1 ============
// tile 10x16 of (100x64); halo 12x18 staged in LDS
__global__ __launch_bounds__(256) void k_ic5(
    const float* __restrict__ t2, const unsigned char* __restrict__ m1,
    const float* __restrict__ u2, const float* __restrict__ bu2,
    const float* __restrict__ w5, const float* __restrict__ b5,
    float* __restrict__ t4){
  __shared__ __align__(16) float vs[12][18][16];
  __shared__ __align__(16) float w5s[144][8];
  __shared__ unsigned char msl[12][18];
  int blk = blockIdx.x;
  int b  = blk / 40;
  int t  = blk % 40;
  int th = t >> 2, tw = t & 3;
  int h0 = th*10, w0 = tw*16;
  int tid = threadIdx.x;
  for (int i=tid;i<144*8;i+=256) w5s[i>>3][i&7] = w5[i];
  if (tid < 216){
    int lr = tid/18, lc = tid%18;
    int h1 = h0-1+lr, w1c = w0-1+lc;
    bool mk = (h1>=0 && h1<NH1 && w1c>=0 && w1c<NW1) && m1[(b*NH1+h1)*NW1+w1c];
    msl[lr][lc] = mk?1:0;
    float acc[16];
    if (mk){
      const float* dp = t2 + (((size_t)b*NH2 + h1/5)*NW2 + w1c/2)*NC2;
      const float* up = u2 + ((h1%5)*2 + (w1c&1))*256;
      #pragma unroll
      for (int co=0;co<16;co++) acc[co]=bu2[co];
      #pragma unroll
      for (int ci=0;ci<16;ci++){
        float dv = dp[ci];
        const float* ur = up + ci*16;
        #pragma unroll
        for (int co=0;co<16;co++) acc[co]=fmaf(dv,ur[co],acc[co]);
      }
    } else {
      #pragma unroll
      for (int co=0;co<16;co++) acc[co]=0.f;
    }
    #pragma unroll
    for (int co=0;co<16;co++) vs[lr][lc][co]=acc[co];
  }
  __syncthreads();
  if (tid < 160){
    int lh = tid/16, lw = tid%16;
    int h1 = h0+lh, w1c = w0+lw;
    float a[8];
    if (msl[lh+1][lw+1]){
      #pragma unroll
      for (int co=0;co<8;co++) a[co]=b5[co];
      #pragma unroll
      for (int kh=0;kh<3;kh++)
      #pragma unroll
      for (int kw=0;kw<3;kw++){
        const float* vp = vs[lh+kh][lw+kw];
        #pragma unroll
        for (int ci=0;ci<16;ci++){
          float v = vp[ci];
          const float* wr = w5s[(kh*3+kw)*16+ci];
          #pragma unroll
          for (int co=0;co<8;co++) a[co]=fmaf(v,wr[co],a[co]);
        }
      }
    } else {
      #pragma unroll
      for (int co=0;co<8;co++) a[co]=0.f;
    }
    float* op = t4 + (((size_t)b*NH1+h1)*NW1+w1c)*NC1;
    #pragma unroll
    for (int co=0;co<8;co++) op[co]=a[co];
  }
}

// ============ fused invconv3 (2,2,8,8) + conv6 (3x3,8->6), mask m0, NCHW out ============
__global__ void k_inv3conv6(const float* __restrict__ t4, const unsigned char* __restrict__ m0,
                            const float* __restrict__ u3, const float* __restrict__ bu3,
                            const float* __restrict__ w6, const float* __restrict__ b6,
                            float* __restrict__ out){
  int idx = blockIdx.x*256+threadIdx.x;
  if (idx >= NB*NH0*NW0) return;
  int w = idx % NW0;
  int t = idx / NW0;
  int h = t % NH0;
  int b = t / NH0;
  float acc[6];
  if (m0[idx]){
    #pragma unroll
    for (int co=0;co<6;co++) acc[co]=b6[co];
    for (int kh=0;kh<3;kh++){
      int hh=h+kh-1; if (hh<0||hh>=NH0) continue;
      for (int kw=0;kw<3;kw++){
        int ww=w+kw-1; if (ww<0||ww>=NW0) continue;
        if (!m0[(b*NH0+hh)*NW0+ww]) continue;
        const float* tp = t4 + (((size_t)b*NH1 + (hh>>1))*NW1 + (ww>>1))*NC1;
        const float* up = u3 + (((hh&1)*2+(ww&1))*NC1)*NC1;
        float v8[NC1];
        #pragma unroll
        for (int c=0;c<NC1;c++){
          float v=bu3[c];
          #pragma unroll
          for (int ci=0;ci<NC1;ci++) v=fmaf(tp[ci],up[ci*NC1+c],v);
          v8[c]=v;
        }
        const float* wpt = w6 + ((kh*3+kw)*NC1)*6;
        #pragma unroll
        for (int ci=0;ci<NC1;ci++)
          #pragma unroll
          for (int co=0;co<6;co++) acc[co]=fmaf(v8[ci],wpt[ci*6+co],acc[co]);
      }
    }
  } else {
    #pragma unroll
    for (int co=0;co<6;co++) acc[co]=0.f;
  }
  size_t base = (size_t)b*6*NH0*NW0 + (size_t)h*NW0 + w;
  #pragma unroll
  for (int co=0;co<6;co++) out[base + (size_t)co*NH0*NW0] = acc[co];
}

extern "C" void kernel_launch(void* const* d_in, const int* in_sizes, int n_in,
                              void* d_out, int out_size, void* d_ws, size_t ws_size,
                              hipStream_t stream){
  (void)in_sizes; (void)n_in; (void)out_size; (void)ws_size;
  const float* x    = (const float*)d_in[0];
  const float* eps  = (const float*)d_in[1];
  const float* w1   = (const float*)d_in[2];
  const float* b1   = (const float*)d_in[3];
  const float* w2   = (const float*)d_in[4];
  const float* b2   = (const float*)d_in[5];
  const float* w3   = (const float*)d_in[6];
  const float* b3   = (const float*)d_in[7];
  const float* wmu  = (const float*)d_in[8];
  const float* bmu  = (const float*)d_in[9];
  const float* wlv  = (const float*)d_in[10];
  const float* blv  = (const float*)d_in[11];
  const float* wlin = (const float*)d_in[12];
  const float* blin = (const float*)d_in[13];
  const float* u1   = (const float*)d_in[14];
  const float* bu1  = (const float*)d_in[15];
  const float* w4   = (const float*)d_in[16];
  const float* b4   = (const float*)d_in[17];
  const float* u2   = (const float*)d_in[18];
  const float* bu2  = (const float*)d_in[19];
  const float* w5   = (const float*)d_in[20];
  const float* b5   = (const float*)d_in[21];
  const float* u3   = (const float*)d_in[22];
  const float* bu3  = (const float*)d_in[23];
  const float* w6   = (const float*)d_in[24];
  const float* b6   = (const float*)d_in[25];
  const float* fW1  = (const float*)d_in[26];
  const float* fb1  = (const float*)d_in[27];
  const float* fW2  = (const float*)d_in[28];
  const float* fb2  = (const float*)d_in[29];
  const float* fW3  = (const float*)d_in[30];
  const float* fb3  = (const float*)d_in[31];

  char* ws = (char*)d_ws;
  unsigned char* m0 = (unsigned char*)(ws);
  unsigned char* m1 = (unsigned char*)(ws + 3276800);
  unsigned char* m2 = (unsigned char*)(ws + 4096000);
  unsigned char* m3 = (unsigned char*)(ws + 4177920);
  float* y1p = (float*)(ws + 4194304);    // 26,214,400 B  [B][100][64][8]
  float* y2p = (float*)(ws + 30408704);   //  5,242,880 B  [B][20][32][16]
  float* y3p = (float*)(ws + 35651584);   //  1,048,576 B  [B][4][16][32]
  float* dec = (float*)(ws + 36700160);   //  1,048,576 B  [B][4][16][32]
  float* t2  = y2p;  // reuse: y2p dead after k_conv3pool
  float* t4  = y1p;  // reuse: y1p dead after k_conv2pool

  float* out   = (float*)d_out;
  float* o_mu  = out + 19660800;
  float* o_lv  = out + 19693568;
  float* o_kld = out + 19726336;
  float* o_zf  = out + 19726464;

  k_conv1pool<<< 3584,256,0,stream>>>(x, w1, b1, y1p, m0, m1);
  k_conv2pool<<< 5120,256,0,stream>>>(y1p, m1, w2, b2, y2p, m2);
  k_conv3pool<<< 1024,256,0,stream>>>(y2p, m2, w3, b3, y3p, m3);
  k_latent   <<<  128, 64,0,stream>>>(y3p, m3, eps, wmu,bmu,wlv,blv,wlin,blin,
                                      fW1,fb1,fW2,fb2,fW3,fb3, o_mu,o_lv,o_kld,o_zf, dec);
  k_ic4      <<<  512,256,0,stream>>>(dec, m2, u1, bu1, w4, b4, t2);
  k_ic5      <<< 5120,256,0,stream>>>(t2, m1, u2, bu2, w5, b5, t4);
  k_inv3conv6<<<12800,256,0,stream>>>(t4, m0, u3, bu3, w6, b6, out);
}